// Round 15
// baseline (949.925 us; speedup 1.0000x reference)
//
#include <hip/hip_runtime.h>

#define NU 50000
#define NI 100000
#define DD 64
#define NN 150000
#define EE 1250000
#define ALPHA 0.1f
#define BB 16384

// out[i] = scale * x0_flat[i], where x0 = concat(user_emb, item_emb), float4-vectorized
__global__ void init_scaled_x0(const float4* __restrict__ u4, const float4* __restrict__ i4,
                               float4* __restrict__ o4, float scale) {
    const long total = (long)NN * DD / 4;      // 2.4M float4
    const long nu4   = (long)NU * DD / 4;      // 800K float4
    for (long i = (long)blockIdx.x * blockDim.x + threadIdx.x; i < total;
         i += (long)gridDim.x * blockDim.x) {
        float4 v = (i < nu4) ? u4[i] : i4[i - nu4];
        v.x *= scale; v.y *= scale; v.z *= scale; v.w *= scale;
        o4[i] = v;
    }
}

// one wave per edge; lane d handles dimension d
__global__ void scatter_edges(const int* __restrict__ erow, const int* __restrict__ ecol,
                              const float* __restrict__ ev, const float* __restrict__ x,
                              float* __restrict__ xn) {
    long tid = (long)blockIdx.x * blockDim.x + threadIdx.x;
    if (tid >= (long)EE * DD) return;
    int e = (int)(tid >> 6);
    int d = (int)(tid & 63);
    int r = erow[e];
    int c = ecol[e];
    float v = (1.0f - ALPHA) * ev[e];
    atomicAdd(&xn[(long)r * DD + d], v * x[(long)c * DD + d]);
}

// one wave per query pair
__global__ void gamma_kernel(const float* __restrict__ x, const int* __restrict__ users,
                             const int* __restrict__ items, float* __restrict__ out) {
    int wave = (blockIdx.x * blockDim.x + threadIdx.x) >> 6;
    int lane = threadIdx.x & 63;
    if (wave >= BB) return;
    int u = users[wave];
    int it = items[wave];
    float p = x[(long)u * DD + lane] * x[((long)NU + it) * DD + lane];
    #pragma unroll
    for (int off = 32; off >= 1; off >>= 1)
        p += __shfl_xor(p, off, 64);
    if (lane == 0) out[wave] = p;
}

extern "C" void kernel_launch(void* const* d_in, const int* in_sizes, int n_in,
                              void* d_out, int out_size, void* d_ws, size_t ws_size,
                              hipStream_t stream) {
    const float* uemb = (const float*)d_in[0];
    const float* iemb = (const float*)d_in[1];
    const float* ev   = (const float*)d_in[2];
    const int*   users= (const int*)d_in[3];
    const int*   items= (const int*)d_in[4];
    const int*   erow = (const int*)d_in[5];
    const int*   ecol = (const int*)d_in[6];
    float* out = (float*)d_out;

    float* A = (float*)d_ws;
    float* Bb = A + (long)NN * DD;

    const float4* u4 = (const float4*)uemb;
    const float4* i4 = (const float4*)iemb;

    // A = x0
    init_scaled_x0<<<2048, 256, 0, stream>>>(u4, i4, (float4*)A, 1.0f);

    float* cur = A;
    float* nxt = Bb;
    const long sthreads = (long)EE * DD;              // 80M
    const int  sblocks  = (int)((sthreads + 255) / 256);

    for (int k = 0; k < 3; ++k) {
        init_scaled_x0<<<2048, 256, 0, stream>>>(u4, i4, (float4*)nxt, ALPHA);
        scatter_edges<<<sblocks, 256, 0, stream>>>(erow, ecol, ev, cur, nxt);
        float* t = cur; cur = nxt; nxt = t;
    }

    gamma_kernel<<<BB / 4, 256, 0, stream>>>(cur, users, items, out);
}

// Round 16
// 634.013 us; speedup vs baseline: 1.4983x; 1.4983x over previous
//
#include <hip/hip_runtime.h>

#define NU 50000
#define NI 100000
#define DD 64
#define NN 150000
#define EE 1250000
#define ALPHA 0.1f
#define BB 16384
#define SCAN_B 1024
#define NBLK ((NN + SCAN_B - 1) / SCAN_B)   // 147

// ---------- CSR build ----------
__global__ void hist_rows(const int* __restrict__ erow, int* __restrict__ rcnt) {
    int e = blockIdx.x * blockDim.x + threadIdx.x;
    if (e < EE) atomicAdd(&rcnt[erow[e]], 1);
}

__global__ void reduce_blocks(const int* __restrict__ rcnt, int* __restrict__ bsum) {
    __shared__ int s[SCAN_B];
    int t = threadIdx.x;
    int gid = blockIdx.x * SCAN_B + t;
    s[t] = (gid < NN) ? rcnt[gid] : 0;
    __syncthreads();
    for (int off = SCAN_B / 2; off > 0; off >>= 1) {
        if (t < off) s[t] += s[t + off];
        __syncthreads();
    }
    if (t == 0) bsum[blockIdx.x] = s[0];
}

__global__ void scan_bsum(int* __restrict__ bsum) {
    __shared__ int s[256];
    int t = threadIdx.x;
    int v = (t < NBLK) ? bsum[t] : 0;
    s[t] = v;
    __syncthreads();
    for (int off = 1; off < 256; off <<= 1) {
        int x = (t >= off) ? s[t - off] : 0;
        __syncthreads();
        s[t] += x;
        __syncthreads();
    }
    if (t < NBLK) bsum[t] = s[t] - v;   // exclusive block offsets
}

__global__ void scan_final(const int* __restrict__ rcnt, const int* __restrict__ bsum,
                           int* __restrict__ rptr) {
    __shared__ int s[SCAN_B];
    int t = threadIdx.x;
    int gid = blockIdx.x * SCAN_B + t;
    int v = (gid < NN) ? rcnt[gid] : 0;
    s[t] = v;
    __syncthreads();
    for (int off = 1; off < SCAN_B; off <<= 1) {
        int x = (t >= off) ? s[t - off] : 0;
        __syncthreads();
        s[t] += x;
        __syncthreads();
    }
    if (gid < NN) rptr[gid] = bsum[blockIdx.x] + s[t] - v;      // exclusive
    if (gid == NN - 1) rptr[NN] = bsum[blockIdx.x] + s[t];      // total = EE
}

__global__ void fill_csr(const int* __restrict__ erow, const int* __restrict__ ecol,
                         const float* __restrict__ ev, const int* __restrict__ rptr,
                         int* __restrict__ rcnt, int* __restrict__ scol,
                         float* __restrict__ sval) {
    int e = blockIdx.x * blockDim.x + threadIdx.x;
    if (e >= EE) return;
    int r = erow[e];
    int c = atomicSub(&rcnt[r], 1) - 1;       // unique slot 0..deg-1 (order irrelevant)
    int pos = rptr[r] + c;
    scol[pos] = ecol[e];
    sval[pos] = (1.0f - ALPHA) * ev[e];       // fold 0.9 into stored weight
}

// ---------- propagation: one wave per row, lane = dim ----------
__global__ void propagate(const int* __restrict__ rptr, const int* __restrict__ scol,
                          const float* __restrict__ sval, const float* __restrict__ x,
                          const float* __restrict__ uemb, const float* __restrict__ iemb,
                          float* __restrict__ xn, int first) {
    int w = (blockIdx.x * blockDim.x + threadIdx.x) >> 6;
    int lane = threadIdx.x & 63;
    if (w >= NN) return;
    int beg = rptr[w], end = rptr[w + 1];
    float acc = 0.0f;
    if (first) {
        for (int j = beg; j < end; ++j) {
            int cc = scol[j];                 // wave-uniform scalar
            float v = sval[j];
            const float* src = (cc < NU) ? (uemb + (long)cc * DD)
                                         : (iemb + (long)(cc - NU) * DD);
            acc += v * src[lane];
        }
    } else {
        for (int j = beg; j < end; ++j) {
            int cc = scol[j];
            float v = sval[j];
            acc += v * x[(long)cc * DD + lane];
        }
    }
    float x0 = (w < NU) ? uemb[(long)w * DD + lane]
                        : iemb[(long)(w - NU) * DD + lane];
    xn[(long)w * DD + lane] = acc + ALPHA * x0;
}

// ---------- final dot products: one wave per pair ----------
__global__ void gamma_kernel(const float* __restrict__ x, const int* __restrict__ users,
                             const int* __restrict__ items, float* __restrict__ out) {
    int wave = (blockIdx.x * blockDim.x + threadIdx.x) >> 6;
    int lane = threadIdx.x & 63;
    if (wave >= BB) return;
    int u = users[wave];
    int it = items[wave];
    float p = x[(long)u * DD + lane] * x[((long)NU + it) * DD + lane];
    #pragma unroll
    for (int off = 32; off >= 1; off >>= 1)
        p += __shfl_xor(p, off, 64);
    if (lane == 0) out[wave] = p;
}

extern "C" void kernel_launch(void* const* d_in, const int* in_sizes, int n_in,
                              void* d_out, int out_size, void* d_ws, size_t ws_size,
                              hipStream_t stream) {
    const float* uemb  = (const float*)d_in[0];
    const float* iemb  = (const float*)d_in[1];
    const float* ev    = (const float*)d_in[2];
    const int*   users = (const int*)d_in[3];
    const int*   items = (const int*)d_in[4];
    const int*   erow  = (const int*)d_in[5];
    const int*   ecol  = (const int*)d_in[6];
    float* out = (float*)d_out;

    // workspace layout (floats/ints are 4 B): A, B node buffers first (16B-aligned)
    float* A    = (float*)d_ws;                    // NN*DD
    float* Bb   = A + (long)NN * DD;               // NN*DD
    int*   rcnt = (int*)(Bb + (long)NN * DD);      // NN
    int*   rptr = rcnt + NN;                       // NN+1
    int*   bsum = rptr + NN + 1;                   // 256 (pad)
    int*   scol = bsum + 256;                      // EE
    float* sval = (float*)(scol + EE);             // EE
    // total ~88.2 MB

    const int eblocks = (EE + 255) / 256;
    const int pblocks = (NN * DD) / 256;           // 37500

    // CSR build (per launch; same work every call)
    hipMemsetAsync(rcnt, 0, NN * sizeof(int), stream);
    hist_rows   <<<eblocks, 256, 0, stream>>>(erow, rcnt);
    reduce_blocks<<<NBLK, SCAN_B, 0, stream>>>(rcnt, bsum);
    scan_bsum   <<<1, 256, 0, stream>>>(bsum);
    scan_final  <<<NBLK, SCAN_B, 0, stream>>>(rcnt, bsum, rptr);
    fill_csr    <<<eblocks, 256, 0, stream>>>(erow, ecol, ev, rptr, rcnt, scol, sval);

    // K=3 pull-propagations: x0 -> A -> B -> A
    propagate<<<pblocks, 256, 0, stream>>>(rptr, scol, sval, nullptr, uemb, iemb, A, 1);
    propagate<<<pblocks, 256, 0, stream>>>(rptr, scol, sval, A,       uemb, iemb, Bb, 0);
    propagate<<<pblocks, 256, 0, stream>>>(rptr, scol, sval, Bb,      uemb, iemb, A, 0);

    gamma_kernel<<<BB / 4, 256, 0, stream>>>(A, users, items, out);
}

// Round 20
// 446.404 us; speedup vs baseline: 2.1279x; 1.4203x over previous
//
#include <hip/hip_runtime.h>

#define NU 50000
#define NI 100000
#define DD 64
#define NN 150000
#define EE 1250000
#define ALPHA 0.1f
#define BB 16384
#define SCAN_B 1024
#define NBLK ((NN + SCAN_B - 1) / SCAN_B)   // 147

// ---------- CSR build ----------
__global__ void hist_rows(const int* __restrict__ erow, int* __restrict__ rcnt) {
    int e = blockIdx.x * blockDim.x + threadIdx.x;
    if (e < EE) atomicAdd(&rcnt[erow[e]], 1);
}

__global__ void reduce_blocks(const int* __restrict__ rcnt, int* __restrict__ bsum) {
    __shared__ int s[SCAN_B];
    int t = threadIdx.x;
    int gid = blockIdx.x * SCAN_B + t;
    s[t] = (gid < NN) ? rcnt[gid] : 0;
    __syncthreads();
    for (int off = SCAN_B / 2; off > 0; off >>= 1) {
        if (t < off) s[t] += s[t + off];
        __syncthreads();
    }
    if (t == 0) bsum[blockIdx.x] = s[0];
}

__global__ void scan_bsum(int* __restrict__ bsum) {
    __shared__ int s[256];
    int t = threadIdx.x;
    int v = (t < NBLK) ? bsum[t] : 0;
    s[t] = v;
    __syncthreads();
    for (int off = 1; off < 256; off <<= 1) {
        int x = (t >= off) ? s[t - off] : 0;
        __syncthreads();
        s[t] += x;
        __syncthreads();
    }
    if (t < NBLK) bsum[t] = s[t] - v;   // exclusive block offsets
}

__global__ void scan_final(const int* __restrict__ rcnt, const int* __restrict__ bsum,
                           int* __restrict__ rptr) {
    __shared__ int s[SCAN_B];
    int t = threadIdx.x;
    int gid = blockIdx.x * SCAN_B + t;
    int v = (gid < NN) ? rcnt[gid] : 0;
    s[t] = v;
    __syncthreads();
    for (int off = 1; off < SCAN_B; off <<= 1) {
        int x = (t >= off) ? s[t - off] : 0;
        __syncthreads();
        s[t] += x;
        __syncthreads();
    }
    if (gid < NN) rptr[gid] = bsum[blockIdx.x] + s[t] - v;      // exclusive
    if (gid == NN - 1) rptr[NN] = bsum[blockIdx.x] + s[t];      // total = EE
}

__global__ void fill_csr(const int* __restrict__ erow, const int* __restrict__ ecol,
                         const float* __restrict__ ev, const int* __restrict__ rptr,
                         int* __restrict__ rcnt, int* __restrict__ scol,
                         float* __restrict__ sval) {
    int e = blockIdx.x * blockDim.x + threadIdx.x;
    if (e >= EE) return;
    int r = erow[e];
    int c = atomicSub(&rcnt[r], 1) - 1;       // unique slot 0..deg-1 (order irrelevant)
    int pos = rptr[r] + c;
    scol[pos] = ecol[e];
    sval[pos] = (1.0f - ALPHA) * ev[e];       // fold 0.9 into stored weight
}

// ---------- propagation v2: one wave per row; 4 lane-groups x 16 lanes ----------
// group g (lane>>4) handles edge j+g; lane reads float4 (16B) of source row.
// After the loop, 2-step shfl_xor(16,32) folds the 4 group partials; lanes 0-15
// add alpha*x0 and store the row as 4x float4 (256B coalesced).
__global__ void propagate(const int* __restrict__ rptr, const int* __restrict__ scol,
                          const float* __restrict__ sval, const float* __restrict__ x,
                          const float* __restrict__ uemb, const float* __restrict__ iemb,
                          float* __restrict__ xn, int first) {
    int w = (blockIdx.x * blockDim.x + threadIdx.x) >> 6;
    int lane = threadIdx.x & 63;
    if (w >= NN) return;
    int beg = rptr[w], end = rptr[w + 1];
    int g = lane >> 4;        // edge subgroup 0..3
    int q = lane & 15;        // float4 index within row (16 x 16B = 256B)

    float4 acc = make_float4(0.f, 0.f, 0.f, 0.f);
    for (int j = beg; j < end; j += 4) {
        int jj = j + g;
        bool valid = jj < end;
        int cc   = valid ? scol[jj] : 0;
        float vv = valid ? sval[jj] : 0.0f;
        const float4* src;
        if (first) {
            src = (cc < NU) ? (const float4*)(uemb + (long)cc * DD)
                            : (const float4*)(iemb + (long)(cc - NU) * DD);
        } else {
            src = (const float4*)(x + (long)cc * DD);
        }
        float4 xv = src[q];
        acc.x += vv * xv.x; acc.y += vv * xv.y;
        acc.z += vv * xv.z; acc.w += vv * xv.w;
    }
    // fold the 4 edge-groups (lanes differing in bits 4,5 share the same dims q)
    #pragma unroll
    for (int off = 16; off <= 32; off <<= 1) {
        acc.x += __shfl_xor(acc.x, off, 64);
        acc.y += __shfl_xor(acc.y, off, 64);
        acc.z += __shfl_xor(acc.z, off, 64);
        acc.w += __shfl_xor(acc.w, off, 64);
    }
    if (lane < 16) {
        const float4* x0p = (w < NU) ? (const float4*)(uemb + (long)w * DD)
                                     : (const float4*)(iemb + (long)(w - NU) * DD);
        float4 x0 = x0p[q];
        float4 r = make_float4(acc.x + ALPHA * x0.x, acc.y + ALPHA * x0.y,
                               acc.z + ALPHA * x0.z, acc.w + ALPHA * x0.w);
        ((float4*)(xn + (long)w * DD))[q] = r;
    }
}

// ---------- final dot products: one wave per pair ----------
__global__ void gamma_kernel(const float* __restrict__ x, const int* __restrict__ users,
                             const int* __restrict__ items, float* __restrict__ out) {
    int wave = (blockIdx.x * blockDim.x + threadIdx.x) >> 6;
    int lane = threadIdx.x & 63;
    if (wave >= BB) return;
    int u = users[wave];
    int it = items[wave];
    float p = x[(long)u * DD + lane] * x[((long)NU + it) * DD + lane];
    #pragma unroll
    for (int off = 32; off >= 1; off >>= 1)
        p += __shfl_xor(p, off, 64);
    if (lane == 0) out[wave] = p;
}

extern "C" void kernel_launch(void* const* d_in, const int* in_sizes, int n_in,
                              void* d_out, int out_size, void* d_ws, size_t ws_size,
                              hipStream_t stream) {
    const float* uemb  = (const float*)d_in[0];
    const float* iemb  = (const float*)d_in[1];
    const float* ev    = (const float*)d_in[2];
    const int*   users = (const int*)d_in[3];
    const int*   items = (const int*)d_in[4];
    const int*   erow  = (const int*)d_in[5];
    const int*   ecol  = (const int*)d_in[6];
    float* out = (float*)d_out;

    // workspace layout
    float* A    = (float*)d_ws;                    // NN*DD
    float* Bb   = A + (long)NN * DD;               // NN*DD
    int*   rcnt = (int*)(Bb + (long)NN * DD);      // NN
    int*   rptr = rcnt + NN;                       // NN+1
    int*   bsum = rptr + NN + 1;                   // 256 (pad)
    int*   scol = bsum + 256;                      // EE
    float* sval = (float*)(scol + EE);             // EE

    const int eblocks = (EE + 255) / 256;
    const int pblocks = (NN * DD) / 256;           // 37500

    // CSR build (per launch; same work every call)
    hipMemsetAsync(rcnt, 0, NN * sizeof(int), stream);
    hist_rows   <<<eblocks, 256, 0, stream>>>(erow, rcnt);
    reduce_blocks<<<NBLK, SCAN_B, 0, stream>>>(rcnt, bsum);
    scan_bsum   <<<1, 256, 0, stream>>>(bsum);
    scan_final  <<<NBLK, SCAN_B, 0, stream>>>(rcnt, bsum, rptr);
    fill_csr    <<<eblocks, 256, 0, stream>>>(erow, ecol, ev, rptr, rcnt, scol, sval);

    // K=3 pull-propagations: x0 -> A -> B -> A
    propagate<<<pblocks, 256, 0, stream>>>(rptr, scol, sval, nullptr, uemb, iemb, A, 1);
    propagate<<<pblocks, 256, 0, stream>>>(rptr, scol, sval, A,       uemb, iemb, Bb, 0);
    propagate<<<pblocks, 256, 0, stream>>>(rptr, scol, sval, Bb,      uemb, iemb, A, 0);

    gamma_kernel<<<BB / 4, 256, 0, stream>>>(A, users, items, out);
}